// Round 6
// baseline (369.494 us; speedup 1.0000x reference)
//
#include <hip/hip_runtime.h>

#define NN 2048   // atoms
#define CA 128    // c_atom
#define CR 389    // c_ref feature dim
#define CP 16     // c_atom_pair

#define ROWS_PER_BLOCK 4
#define CL_BLOCKS  (NN / 8)              // 256 cl blocks, 8 atoms each (first in grid)
#define PLM_BLOCKS (NN / ROWS_PER_BLOCK) // 512 plm blocks, 4 consecutive rows each

typedef float nfloat4 __attribute__((ext_vector_type(4)));

// Fused kernel, 256 threads/block.
//   blocks [0, 256)   -> cl (dispatch first, fully hidden under plm)
//   blocks [256, 768) -> plm, 4 consecutive rows per block written in strict
//                        address order (512 KB sequential stream per block).
// Rationale: harness fill kernel hits 6.4 TB/s with ~256 sequential streams;
// R2/R4/R5 used 2048 concurrent 128 KB streams -> DRAM row thrash -> ~2 TB/s.
// Stores: wave-instr = 64 lanes x 16 B = 1 KB contiguous, nontemporal
// (measured >= plain stores; keeps L1/L2 clean for pos/uid/Wf reuse).
__global__ __launch_bounds__(256) void fused_kernel(
    const float* __restrict__ pos, const float* __restrict__ charge,
    const float* __restrict__ mask, const float* __restrict__ elem,
    const float* __restrict__ names, const float* __restrict__ Wf,
    const float* __restrict__ bfeats,
    const int* __restrict__ uid,
    const float* __restrict__ Woff, const float* __restrict__ boff,
    const float* __restrict__ Winv, const float* __restrict__ binv,
    const float* __restrict__ Wvm, const float* __restrict__ bvm,
    float* __restrict__ cl, float* __restrict__ plm)
{
    __shared__ float ft[8][CR];
    const int tid = threadIdx.x;

    if (blockIdx.x >= CL_BLOCKS) {
        // ---------------- plm: 4 consecutive rows, sequential writes ----------------
        const int l0 = (blockIdx.x - CL_BLOCKS) * ROWS_PER_BLOCK;
        const int q = tid & 3;              // channel quad: channels 4q..4q+3
        const int p = tid >> 2;             // pair slot 0..63

        float w0[4], w1[4], w2[4], wi[4], kk[4];
        #pragma unroll
        for (int i = 0; i < 4; ++i) {
            int c = q * 4 + i;
            w0[i] = Woff[c];
            w1[i] = Woff[CP + c];
            w2[i] = Woff[2 * CP + c];
            wi[i] = Winv[c];
            kk[i] = Wvm[c] + boff[c] + binv[c] + bvm[c];
        }

        for (int r = 0; r < ROWS_PER_BLOCK; ++r) {
            const int l = l0 + r;
            const float plx = pos[l * 3 + 0];
            const float ply = pos[l * 3 + 1];
            const float plz = pos[l * 3 + 2];
            const int ul = uid[l];
            nfloat4* __restrict__ dst = (nfloat4*)(plm + (size_t)l * NN * CP);

            #pragma unroll 4
            for (int j = 0; j < NN / 64; ++j) {   // 32 iters; block writes 4 KB/iter, in order
                const int m = j * 64 + p;
                const float dx = plx - pos[m * 3 + 0];
                const float dy = ply - pos[m * 3 + 1];
                const float dz = plz - pos[m * 3 + 2];
                const float inv = 1.0f / (1.0f + dx * dx + dy * dy + dz * dz);
                const unsigned sel = (uid[m] == ul) ? 0xFFFFFFFFu : 0u;

                float rx = fmaf(dx, w0[0], fmaf(dy, w1[0], fmaf(dz, w2[0], fmaf(inv, wi[0], kk[0]))));
                float ry = fmaf(dx, w0[1], fmaf(dy, w1[1], fmaf(dz, w2[1], fmaf(inv, wi[1], kk[1]))));
                float rz = fmaf(dx, w0[2], fmaf(dy, w1[2], fmaf(dz, w2[2], fmaf(inv, wi[2], kk[2]))));
                float rw = fmaf(dx, w0[3], fmaf(dy, w1[3], fmaf(dz, w2[3], fmaf(inv, wi[3], kk[3]))));

                nfloat4 rr;
                rr.x = __uint_as_float(__float_as_uint(rx) & sel);   // v==0 -> exact +0.0f
                rr.y = __uint_as_float(__float_as_uint(ry) & sel);
                rr.z = __uint_as_float(__float_as_uint(rz) & sel);
                rr.w = __uint_as_float(__float_as_uint(rw) & sel);

                __builtin_nontemporal_store(rr, dst + j * 256 + tid);  // 1 KB contiguous/wave
            }
        }
    } else {
        // ---------------- cl: 8 atoms per block ----------------
        const int n0 = blockIdx.x * 8;

        // Stage concatenated features [pos(3),charge(1),mask(1),elem(128),names(256)]
        for (int idx = tid; idx < 8 * CR; idx += 256) {
            int a = idx / CR;
            int k = idx - a * CR;          // consecutive k -> coalesced elem/names
            int n = n0 + a;
            float v;
            if (k < 3)         v = pos[n * 3 + k];
            else if (k == 3)   v = charge[n];
            else if (k == 4)   v = mask[n];
            else if (k < 133)  v = elem[n * 128 + (k - 5)];
            else               v = names[n * 256 + (k - 133)];
            ft[a][k] = v;
        }
        __syncthreads();

        const int c = tid & 127;
        const int half = tid >> 7;          // atoms half*4 .. half*4+3
        float a0 = 0.f, a1 = 0.f, a2 = 0.f, a3 = 0.f;
        #pragma unroll 4                     // 4 Wf loads in flight, 4x reg reuse each
        for (int k = 0; k < CR; ++k) {
            const float w = Wf[k * CA + c];  // coalesced across c, L1/L2-resident
            a0 = fmaf(ft[half * 4 + 0][k], w, a0);   // LDS broadcast reads
            a1 = fmaf(ft[half * 4 + 1][k], w, a1);
            a2 = fmaf(ft[half * 4 + 2][k], w, a2);
            a3 = fmaf(ft[half * 4 + 3][k], w, a3);
        }
        const float bb = bfeats[c];
        const int nb = n0 + half * 4;
        cl[(size_t)(nb + 0) * CA + c] = a0 + bb;
        cl[(size_t)(nb + 1) * CA + c] = a1 + bb;
        cl[(size_t)(nb + 2) * CA + c] = a2 + bb;
        cl[(size_t)(nb + 3) * CA + c] = a3 + bb;
    }
}

extern "C" void kernel_launch(void* const* d_in, const int* in_sizes, int n_in,
                              void* d_out, int out_size, void* d_ws, size_t ws_size,
                              hipStream_t stream)
{
    const float* pos    = (const float*)d_in[0];
    const float* charge = (const float*)d_in[1];
    const float* mask   = (const float*)d_in[2];
    const float* elem   = (const float*)d_in[3];
    const float* names  = (const float*)d_in[4];
    const int*   uid    = (const int*)  d_in[5];
    const float* Wf     = (const float*)d_in[6];
    const float* bfeats = (const float*)d_in[7];
    const float* Woff   = (const float*)d_in[8];
    const float* boff   = (const float*)d_in[9];
    const float* Winv   = (const float*)d_in[10];
    const float* binv   = (const float*)d_in[11];
    const float* Wvm    = (const float*)d_in[12];
    const float* bvm    = (const float*)d_in[13];

    float* cl  = (float*)d_out;
    float* plm = (float*)d_out + (size_t)NN * CA;

    fused_kernel<<<CL_BLOCKS + PLM_BLOCKS, 256, 0, stream>>>(
        pos, charge, mask, elem, names, Wf, bfeats, uid,
        Woff, boff, Winv, binv, Wvm, bvm, cl, plm);
}

// Round 7
// 352.362 us; speedup vs baseline: 1.0486x; 1.0486x over previous
//
#include <hip/hip_runtime.h>

#define NN 2048   // atoms
#define CA 128    // c_atom
#define CR 389    // c_ref feature dim
#define CP 16     // c_atom_pair

#define CL_BLOCKS   256                  // 8 atoms each
#define PLM_BLOCKS  512                  // 512 x 256 thr = 2^17 threads, grid-stride
#define PLM_G       (PLM_BLOCKS * 256)   // 131072 = 2^17
#define PLM_CHUNKS  (NN * NN * CP / 4)   // 16.8M float4 chunks
#define PLM_ITERS   (PLM_CHUNKS / PLM_G) // 128

// plm[l][m][c] = v * (dlm . Woff[:,c] + inv_sq*Winv[c] + K[c]),
//   K[c] = Wvm[c]+boff[c]+binv[c]+bvm[c]  (v in {0,1}, v^2=v)
//
// plm is written FILL-SHAPED: flat float4 index f = g + i*2^17 (same dense
// lockstep-sweeping address window as the 6.4 TB/s harness fill; R4-R6's
// per-block private regions scattered the live write set -> DRAM row thrash
// at ~2 TB/s regardless of stream count). With G=2^17:
//   q = g&3, m = (g>>2)&2047  -> loop-invariant (weights/M-pos/uid hoisted)
//   l = (g>>13) + 16*i        -> wave-uniform  -> scalar pos/uid loads
__global__ __launch_bounds__(256) void fused_kernel(
    const float* __restrict__ pos, const float* __restrict__ charge,
    const float* __restrict__ mask, const float* __restrict__ elem,
    const float* __restrict__ names, const float* __restrict__ Wf,
    const float* __restrict__ bfeats,
    const int* __restrict__ uid,
    const float* __restrict__ Woff, const float* __restrict__ boff,
    const float* __restrict__ Winv, const float* __restrict__ binv,
    const float* __restrict__ Wvm, const float* __restrict__ bvm,
    float* __restrict__ cl, float* __restrict__ plm)
{
    __shared__ float ft[8][CR];
    const int tid = threadIdx.x;

    if (blockIdx.x >= CL_BLOCKS) {
        // ---------------- plm: grid-stride dense-window writes ----------------
        const int g  = (blockIdx.x - CL_BLOCKS) * 256 + tid;
        const int q  = g & 3;               // channel quad (invariant)
        const int mm = (g >> 2) & (NN - 1); // pair column m (invariant!)
        const int lb = g >> 13;             // l base in [0,16)

        float w0[4], w1[4], w2[4], wi[4], kk[4];
        #pragma unroll
        for (int i = 0; i < 4; ++i) {
            int c = q * 4 + i;
            w0[i] = Woff[c];
            w1[i] = Woff[CP + c];
            w2[i] = Woff[2 * CP + c];
            wi[i] = Winv[c];
            kk[i] = Wvm[c] + boff[c] + binv[c] + bvm[c];
        }
        const float mx = pos[mm * 3 + 0];   // hoisted: m fixed per thread
        const float my = pos[mm * 3 + 1];
        const float mz = pos[mm * 3 + 2];
        const int   um = uid[mm];

        float4* __restrict__ dst = (float4*)plm;

        #pragma unroll 4
        for (int i = 0; i < PLM_ITERS; ++i) {
            const int l  = lb + (i << 4);
            const int lu = __builtin_amdgcn_readfirstlane(l);  // wave-uniform -> s_load
            const float dx = pos[lu * 3 + 0] - mx;
            const float dy = pos[lu * 3 + 1] - my;
            const float dz = pos[lu * 3 + 2] - mz;
            const float inv = 1.0f / (1.0f + dx * dx + dy * dy + dz * dz);
            const unsigned sel = (uid[lu] == um) ? 0xFFFFFFFFu : 0u;

            float rx = fmaf(dx, w0[0], fmaf(dy, w1[0], fmaf(dz, w2[0], fmaf(inv, wi[0], kk[0]))));
            float ry = fmaf(dx, w0[1], fmaf(dy, w1[1], fmaf(dz, w2[1], fmaf(inv, wi[1], kk[1]))));
            float rz = fmaf(dx, w0[2], fmaf(dy, w1[2], fmaf(dz, w2[2], fmaf(inv, wi[2], kk[2]))));
            float rw = fmaf(dx, w0[3], fmaf(dy, w1[3], fmaf(dz, w2[3], fmaf(inv, wi[3], kk[3]))));

            float4 r;   // v==0 -> exact +0.0f via bitwise AND (every element written)
            r.x = __uint_as_float(__float_as_uint(rx) & sel);
            r.y = __uint_as_float(__float_as_uint(ry) & sel);
            r.z = __uint_as_float(__float_as_uint(rz) & sel);
            r.w = __uint_as_float(__float_as_uint(rw) & sel);

            dst[(unsigned)g + (unsigned)i * PLM_G] = r;  // dense sweeping window
        }
    } else {
        // ---------------- cl: 8 atoms per block ----------------
        const int n0 = blockIdx.x * 8;

        // Stage concatenated features [pos(3),charge(1),mask(1),elem(128),names(256)]
        for (int idx = tid; idx < 8 * CR; idx += 256) {
            int a = idx / CR;
            int k = idx - a * CR;          // consecutive k -> coalesced elem/names
            int n = n0 + a;
            float v;
            if (k < 3)         v = pos[n * 3 + k];
            else if (k == 3)   v = charge[n];
            else if (k == 4)   v = mask[n];
            else if (k < 133)  v = elem[n * 128 + (k - 5)];
            else               v = names[n * 256 + (k - 133)];
            ft[a][k] = v;
        }
        __syncthreads();

        const int c = tid & 127;
        const int half = tid >> 7;          // atoms half*4 .. half*4+3
        float a0 = 0.f, a1 = 0.f, a2 = 0.f, a3 = 0.f;
        #pragma unroll 4                     // 4 Wf loads in flight, 4x reg reuse each
        for (int k = 0; k < CR; ++k) {
            const float w = Wf[k * CA + c];  // coalesced across c, L1/L2-resident
            a0 = fmaf(ft[half * 4 + 0][k], w, a0);   // LDS broadcast reads
            a1 = fmaf(ft[half * 4 + 1][k], w, a1);
            a2 = fmaf(ft[half * 4 + 2][k], w, a2);
            a3 = fmaf(ft[half * 4 + 3][k], w, a3);
        }
        const float bb = bfeats[c];
        const int nb = n0 + half * 4;
        cl[(size_t)(nb + 0) * CA + c] = a0 + bb;
        cl[(size_t)(nb + 1) * CA + c] = a1 + bb;
        cl[(size_t)(nb + 2) * CA + c] = a2 + bb;
        cl[(size_t)(nb + 3) * CA + c] = a3 + bb;
    }
}

extern "C" void kernel_launch(void* const* d_in, const int* in_sizes, int n_in,
                              void* d_out, int out_size, void* d_ws, size_t ws_size,
                              hipStream_t stream)
{
    const float* pos    = (const float*)d_in[0];
    const float* charge = (const float*)d_in[1];
    const float* mask   = (const float*)d_in[2];
    const float* elem   = (const float*)d_in[3];
    const float* names  = (const float*)d_in[4];
    const int*   uid    = (const int*)  d_in[5];
    const float* Wf     = (const float*)d_in[6];
    const float* bfeats = (const float*)d_in[7];
    const float* Woff   = (const float*)d_in[8];
    const float* boff   = (const float*)d_in[9];
    const float* Winv   = (const float*)d_in[10];
    const float* binv   = (const float*)d_in[11];
    const float* Wvm    = (const float*)d_in[12];
    const float* bvm    = (const float*)d_in[13];

    float* cl  = (float*)d_out;
    float* plm = (float*)d_out + (size_t)NN * CA;

    fused_kernel<<<CL_BLOCKS + PLM_BLOCKS, 256, 0, stream>>>(
        pos, charge, mask, elem, names, Wf, bfeats, uid,
        Woff, boff, Winv, binv, Wvm, bvm, cl, plm);
}